// Round 5
// baseline (332.634 us; speedup 1.0000x reference)
//
#include <hip/hip_runtime.h>
#include <hip/hip_bf16.h>

// LinearSim: out = X @ W.T + Bias (reference normalizations cancel exactly).
// M=65536, K=512, N=512, f32 in/out, bf16 MFMA inside.
// R4 post-mortem: reg-staged prefetch serialized (dur 139->170), nt stores
// amplified writes (142->203MB). R5 structure:
//  - A tile: global_load_lds f32 DMA (async, no VGPR round-trip), double-buf,
//    source-swizzled so LDS reads are conflict-free; cvt f32->bf16 at read.
//  - B (W panel, 1MB total): straight global->reg each step, L2-resident
//    (XCD-grouping swizzle keeps all of W + shared X panels in each L2).
//  - one barrier per K-step (auto vmcnt drain = DMA wait).
//  - plain stores (no nt).

typedef __bf16 bf16x8 __attribute__((ext_vector_type(8)));
typedef float  f32x4  __attribute__((ext_vector_type(4)));

constexpr int M_TOK = 65536;
constexpr int K_IN  = 512;
constexpr int N_OUT = 512;

constexpr int BM = 128, BN = 128, BK = 32;
constexpr int NT = K_IN / BK;   // 16 K-steps

__global__ __launch_bounds__(256, 3)
void linear_sim_kernel(const float* __restrict__ X,
                       const float* __restrict__ W,
                       const float* __restrict__ Bias,
                       float* __restrict__ Out)
{
    // A only in LDS: [buf][row 0..127][8 chunks of 4 f32], linear (DMA dest),
    // content swizzled: LDS[r][p] holds global chunk (p ^ (r&7)) of row r.
    __shared__ float As[2][BM][BK];   // 2 * 16 KB

    // XCD-grouping swizzle (bijective, 2048 % 8 == 0): each XCD gets a
    // contiguous run of logical tiles; 4 N-siblings of an M-panel share L2.
    const int d  = blockIdx.x;
    const int o  = (d & 7) * 256 + (d >> 3);
    const int nb = o & 3;
    const int mb = o >> 2;
    const int m0 = mb * BM, n0 = nb * BN;

    const int tid  = threadIdx.x;
    const int lane = tid & 63;
    const int w    = tid >> 6;        // wave 0..3, 2x2 grid of 64x64 tiles
    const int wm = w >> 1, wn = w & 1;
    const int l15 = lane & 15, lg = lane >> 4;

    // DMA source swizzle: lane l covers row (base + l>>3), chunk position l&7;
    // content must be global chunk (l&7) ^ (l>>3).
    const int lrow8  = lane >> 3;               // = r & 7 for this lane
    const int gchunk = (lane & 7) ^ lrow8;      // pre-swizzled source chunk

    // B fragment row pointers (k-offset lg*8 baked in)
    const float* Wrow[4];
    #pragma unroll
    for (int i = 0; i < 4; ++i)
        Wrow[i] = W + (size_t)(n0 + wn * 64 + i * 16 + l15) * K_IN + lg * 8;

    f32x4 acc[16];
    #pragma unroll
    for (int i = 0; i < 16; ++i) acc[i] = (f32x4){0.f, 0.f, 0.f, 0.f};

    const float* Xbase = X + (size_t)m0 * K_IN;

    // Issue the 16 KB A-tile DMA for K-step t into buffer b.
    // Per thread: 4 x global_load_lds of 16 B. LDS dest is wave-uniform base
    // (+ lane*16 added by HW); global source is per-lane (pre-swizzled).
    auto dma_tile = [&](int t, int b) {
        const int k0 = t * BK;
        #pragma unroll
        for (int j = 0; j < 4; ++j) {
            const int rbase = (j * 4 + w) * 8;            // wave-uniform
            const float* src = Xbase + (size_t)(rbase + lrow8) * K_IN + k0 + gchunk * 4;
            float* dst = &As[b][rbase][0];                // wave-uniform
            __builtin_amdgcn_global_load_lds(
                (const __attribute__((address_space(1))) void*)src,
                (__attribute__((address_space(3))) void*)dst, 16, 0, 0);
        }
    };

    dma_tile(0, 0);
    __syncthreads();   // drains DMA (compiler emits vmcnt(0) before barrier)

    for (int t = 0; t < NT; ++t) {
        const int cur = t & 1;

        // ---- B fragments from global FIRST (so their in-order vmcnt wait
        //      does not force the later-issued DMAs to complete) ----
        const int k0 = t * BK;
        f32x4 wbf[8];
        #pragma unroll
        for (int i = 0; i < 4; ++i) {
            wbf[i * 2]     = *(const f32x4*)(Wrow[i] + k0);
            wbf[i * 2 + 1] = *(const f32x4*)(Wrow[i] + k0 + 4);
        }

        // ---- async DMA of next A tile into the other buffer ----
        if (t + 1 < NT) dma_tile(t + 1, cur ^ 1);

        // ---- A fragments from swizzled LDS, cvt f32->bf16 ----
        bf16x8 af[4], bfr[4];
        #pragma unroll
        for (int mi = 0; mi < 4; ++mi) {
            const int r  = wm * 64 + mi * 16 + l15;
            const int rx = l15 & 7;                       // r & 7
            f32x4 c0 = *(const f32x4*)&As[cur][r][((2 * lg)     ^ rx) * 4];
            f32x4 c1 = *(const f32x4*)&As[cur][r][((2 * lg + 1) ^ rx) * 4];
            bf16x8 v;
            #pragma unroll
            for (int e = 0; e < 4; ++e) { v[e] = (__bf16)c0[e]; v[4 + e] = (__bf16)c1[e]; }
            af[mi] = v;
        }
        #pragma unroll
        for (int i = 0; i < 4; ++i) {
            bf16x8 v;
            #pragma unroll
            for (int e = 0; e < 4; ++e) {
                v[e]     = (__bf16)wbf[i * 2][e];
                v[4 + e] = (__bf16)wbf[i * 2 + 1][e];
            }
            bfr[i] = v;
        }

        #pragma unroll
        for (int mi = 0; mi < 4; ++mi)
            #pragma unroll
            for (int ni = 0; ni < 4; ++ni)
                acc[mi * 4 + ni] = __builtin_amdgcn_mfma_f32_16x16x32_bf16(
                    af[mi], bfr[ni], acc[mi * 4 + ni], 0, 0, 0);

        __syncthreads();   // all waves done reading As[cur]; DMA t+1 drained
    }

    // ---- epilogue: C/D layout col = lane&15, row = (lane>>4)*4 + reg ----
    #pragma unroll
    for (int ni = 0; ni < 4; ++ni) {
        const int col = n0 + wn * 64 + ni * 16 + l15;
        const float bv = Bias[col];
        #pragma unroll
        for (int mi = 0; mi < 4; ++mi) {
            const int row0 = m0 + wm * 64 + mi * 16 + lg * 4;
            f32x4 a = acc[mi * 4 + ni];
            #pragma unroll
            for (int r = 0; r < 4; ++r)
                Out[(size_t)(row0 + r) * N_OUT + col] = a[r] + bv;
        }
    }
}

extern "C" void kernel_launch(void* const* d_in, const int* in_sizes, int n_in,
                              void* d_out, int out_size, void* d_ws, size_t ws_size,
                              hipStream_t stream) {
    const float* X    = (const float*)d_in[0];
    const float* W    = (const float*)d_in[1];
    const float* Bias = (const float*)d_in[2];
    float* Out        = (float*)d_out;

    dim3 grid((M_TOK / BM) * (N_OUT / BN));   // 2048 blocks
    linear_sim_kernel<<<grid, dim3(256), 0, stream>>>(X, W, Bias, Out);
}